// Round 1
// baseline (243.949 us; speedup 1.0000x reference)
//
#include <hip/hip_runtime.h>

// LIF activation: x [B=64, T=500, C=1024] fp32, scalars w_input, w_leak.
// Recurrence over t per (b,c):
//   forget = (Vm < 1.0)            // step(1 - Vm)
//   Vm     = relu(wi*x_t + kl*Vm*forget)   kl = 1 - w_leak
//   spike  = (Vm > 1.0)            // step(Vm - 1)
// Output spikes [B, T, C] fp32.
//
// Memory-bound (131 MB in + 131 MB out). One thread per (b,c), 65536 threads.
// T chunked by U=20 with register double-buffering so each wave keeps ~20
// loads in flight (grid-wide ~5 MB) to cover HBM latency at 4 waves/CU.
// __fmul_rn/__fadd_rn prevent FMA contraction: spikes are exact step
// functions and must match numpy's unfused fp32 arithmetic bit-for-bit.

#define LIF_B 64
#define LIF_T 500
#define LIF_C 1024
#define LIF_U 20              // time chunk (500 = 25 * 20)
#define LIF_NCH (LIF_T / LIF_U)

__global__ __launch_bounds__(256) void lif_kernel(
    const float* __restrict__ x,
    const float* __restrict__ w_input_p,
    const float* __restrict__ w_leak_p,
    float* __restrict__ out) {

  const int tid = blockIdx.x * blockDim.x + threadIdx.x;  // 0 .. 65535
  const int b = tid >> 10;          // / 1024
  const int c = tid & (LIF_C - 1);  // % 1024

  const float wi = w_input_p[0];
  const float kl = __fsub_rn(1.0f, w_leak_p[0]);  // 1 - w_leak, fp32, unfused

  const float* xp = x   + (size_t)b * LIF_T * LIF_C + c;
  float*       op = out + (size_t)b * LIF_T * LIF_C + c;

  float buf[2][LIF_U];

  // Preload chunk 0
#pragma unroll
  for (int u = 0; u < LIF_U; ++u) {
    buf[0][u] = xp[(size_t)u * LIF_C];
  }

  float Vm = 0.0f;

  for (int k = 0; k < LIF_NCH; ++k) {
    const int cur = k & 1;

    // Prefetch next chunk (issued before compute; results used next iter)
    if (k + 1 < LIF_NCH) {
      const float* xn = xp + (size_t)(k + 1) * LIF_U * LIF_C;
#pragma unroll
      for (int u = 0; u < LIF_U; ++u) {
        buf[cur ^ 1][u] = xn[(size_t)u * LIF_C];
      }
    }

    float* on = op + (size_t)k * LIF_U * LIF_C;
#pragma unroll
    for (int u = 0; u < LIF_U; ++u) {
      const float xt = buf[cur][u];
      // (1-wl)*Vm*forget with forget in {0,1}: select, exact vs numpy
      const float acc = (Vm < 1.0f) ? __fmul_rn(kl, Vm) : 0.0f;
      const float v   = __fadd_rn(__fmul_rn(wi, xt), acc);
      Vm = fmaxf(v, 0.0f);                       // relu
      on[(size_t)u * LIF_C] = (Vm > 1.0f) ? 1.0f : 0.0f;  // step(Vm - 1)
    }
  }
}

extern "C" void kernel_launch(void* const* d_in, const int* in_sizes, int n_in,
                              void* d_out, int out_size, void* d_ws, size_t ws_size,
                              hipStream_t stream) {
  const float* x  = (const float*)d_in[0];
  const float* wi = (const float*)d_in[1];
  const float* wl = (const float*)d_in[2];
  float* out = (float*)d_out;

  const int n_threads = LIF_B * LIF_C;  // 65536
  const int block = 256;
  const int grid = n_threads / block;   // 256 blocks -> ~1 block/CU
  lif_kernel<<<grid, block, 0, stream>>>(x, wi, wl, out);
}

// Round 2
// 234.997 us; speedup vs baseline: 1.0381x; 1.0381x over previous
//
#include <hip/hip_runtime.h>

// LIF activation: x [B=64, T=500, C=1024] fp32, scalars w_input, w_leak.
// Per (b,c): forget=(Vm<1); Vm=relu(wi*x_t + kl*Vm*forget); spike=(Vm>1).
// Output spikes [B, T, C] fp32. Memory-bound: 131 MB in + 125 MB out.
//
// R1 lesson: buf[cur][u] with runtime `cur` put the double buffer in SCRATCH
// (VGPR_Count=40, WRITE_SIZE 2x output = spill stream). This version peels
// the double buffer into two named register arrays with all indices
// compile-time constant, so it stays in VGPRs (only 4 waves/CU -> up to 512
// VGPRs/wave available; ~100 is free).
//
// U=25 (500 = 20 chunks, even count -> clean 2-way peel). Each wave keeps
// 25 loads (6.4 KB) in flight; 4 waves/CU -> ~26 KB/CU -> ~6.6 MB grid-wide,
// well above the ~2.4 MB latency-BW product.
//
// __fmul_rn/__fadd_rn: spikes are exact step functions vs threshold 1.0 and
// must match numpy's unfused fp32 arithmetic bit-for-bit (verified absmax=0).

#define LIF_B 64
#define LIF_T 500
#define LIF_C 1024
#define LIF_U 25              // time chunk
#define LIF_NCH (LIF_T / LIF_U)  // 20 chunks, even

__global__ __launch_bounds__(256) void lif_kernel(
    const float* __restrict__ x,
    const float* __restrict__ w_input_p,
    const float* __restrict__ w_leak_p,
    float* __restrict__ out) {

  const int tid = blockIdx.x * blockDim.x + threadIdx.x;  // 0 .. 65535
  const int b = tid >> 10;          // / 1024
  const int c = tid & (LIF_C - 1);  // % 1024

  const float wi = w_input_p[0];
  const float kl = __fsub_rn(1.0f, w_leak_p[0]);  // 1 - w_leak

  const float* xp = x   + (size_t)b * LIF_T * LIF_C + c;
  float*       op = out + (size_t)b * LIF_T * LIF_C + c;

  float bufA[LIF_U];
  float bufB[LIF_U];
  float Vm = 0.0f;

  // Preload chunk 0 into bufA
#pragma unroll
  for (int u = 0; u < LIF_U; ++u) {
    bufA[u] = xp[(size_t)u * LIF_C];
  }

  for (int k = 0; k < LIF_NCH; k += 2) {
    // Prefetch chunk k+1 into bufB (always exists: k <= NCH-2)
    {
      const float* xn = xp + (size_t)(k + 1) * LIF_U * LIF_C;
#pragma unroll
      for (int u = 0; u < LIF_U; ++u) {
        bufB[u] = xn[(size_t)u * LIF_C];
      }
    }

    // Compute chunk k from bufA
    {
      float* on = op + (size_t)k * LIF_U * LIF_C;
#pragma unroll
      for (int u = 0; u < LIF_U; ++u) {
        const float xt = bufA[u];
        const float acc = (Vm < 1.0f) ? __fmul_rn(kl, Vm) : 0.0f;
        const float v   = __fadd_rn(__fmul_rn(wi, xt), acc);
        Vm = fmaxf(v, 0.0f);
        on[(size_t)u * LIF_C] = (Vm > 1.0f) ? 1.0f : 0.0f;
      }
    }

    // Prefetch chunk k+2 into bufA (skip on last pair)
    if (k + 2 < LIF_NCH) {
      const float* xn = xp + (size_t)(k + 2) * LIF_U * LIF_C;
#pragma unroll
      for (int u = 0; u < LIF_U; ++u) {
        bufA[u] = xn[(size_t)u * LIF_C];
      }
    }

    // Compute chunk k+1 from bufB
    {
      float* on = op + (size_t)(k + 1) * LIF_U * LIF_C;
#pragma unroll
      for (int u = 0; u < LIF_U; ++u) {
        const float xt = bufB[u];
        const float acc = (Vm < 1.0f) ? __fmul_rn(kl, Vm) : 0.0f;
        const float v   = __fadd_rn(__fmul_rn(wi, xt), acc);
        Vm = fmaxf(v, 0.0f);
        on[(size_t)u * LIF_C] = (Vm > 1.0f) ? 1.0f : 0.0f;
      }
    }
  }
}

extern "C" void kernel_launch(void* const* d_in, const int* in_sizes, int n_in,
                              void* d_out, int out_size, void* d_ws, size_t ws_size,
                              hipStream_t stream) {
  const float* x  = (const float*)d_in[0];
  const float* wi = (const float*)d_in[1];
  const float* wl = (const float*)d_in[2];
  float* out = (float*)d_out;

  const int n_threads = LIF_B * LIF_C;  // 65536
  const int block = 256;
  const int grid = n_threads / block;   // 256 blocks
  lif_kernel<<<grid, block, 0, stream>>>(x, wi, wl, out);
}

// Round 3
// 234.421 us; speedup vs baseline: 1.0406x; 1.0025x over previous
//
#include <hip/hip_runtime.h>

// LIF activation: x [B=64, T=500, C=1024] fp32, scalars w_input, w_leak.
// Per (b,c): forget=(Vm<1); Vm=relu(wi*x_t + kl*Vm*forget); spike=(Vm>1).
// Output spikes [B, T, C] fp32. One thread per (b,c) sequence (65536 threads).
//
// R1: runtime-indexed buf -> scratch spills (WRITE 2x).
// R2: named double buffers, but VGPR_Count=52 showed the compiler sank each
//     load to its use -> only ~10 loads in flight -> latency-bound at 82 us
//     (VALUBusy 9.8%, Occupancy 9.6%).
// R3 (this): QUAD register buffers (4 x 25 floats) + asm memory-clobber
//     barriers after each prefetch batch so all 25 loads of a batch must be
//     live before compute. Steady state: ~60 outstanding dword loads/thread
//     (vmcnt cap 63) -> ~60 KB/CU -> ~15 MB in flight chip-wide, above the
//     ~6 MB latency-BW product. 4 waves/CU, 1 wave/SIMD -> VGPR budget 512,
//     ~150 used is fine.
//
// __fmul_rn/__fadd_rn: spikes are exact step functions vs threshold 1.0;
// must match numpy's unfused fp32 arithmetic bit-for-bit (absmax=0 so far).

#define LIF_B 64
#define LIF_T 500
#define LIF_C 1024
#define LIF_U 25                  // time steps per buffer
#define LIF_NCH (LIF_T / LIF_U)   // 20 chunks, peeled by 4

#define PREFETCH(buf, kk)                                     \
  do {                                                        \
    const float* xn = xp + (size_t)(kk) * LIF_U * LIF_C;      \
    _Pragma("unroll")                                         \
    for (int u = 0; u < LIF_U; ++u) {                         \
      buf[u] = xn[(size_t)u * LIF_C];                         \
    }                                                         \
    __asm__ volatile("" ::: "memory");                        \
  } while (0)

#define COMPUTE(buf, kk)                                      \
  do {                                                        \
    float* on = op + (size_t)(kk) * LIF_U * LIF_C;            \
    _Pragma("unroll")                                         \
    for (int u = 0; u < LIF_U; ++u) {                         \
      const float xt = buf[u];                                \
      const float acc = (Vm < 1.0f) ? __fmul_rn(kl, Vm) : 0.0f; \
      const float v   = __fadd_rn(__fmul_rn(wi, xt), acc);    \
      Vm = fmaxf(v, 0.0f);                                    \
      on[(size_t)u * LIF_C] = (Vm > 1.0f) ? 1.0f : 0.0f;      \
    }                                                         \
  } while (0)

__global__ __launch_bounds__(256, 1) void lif_kernel(
    const float* __restrict__ x,
    const float* __restrict__ w_input_p,
    const float* __restrict__ w_leak_p,
    float* __restrict__ out) {

  const int tid = blockIdx.x * blockDim.x + threadIdx.x;  // 0 .. 65535
  const int b = tid >> 10;          // / 1024
  const int c = tid & (LIF_C - 1);  // % 1024

  const float wi = w_input_p[0];
  const float kl = __fsub_rn(1.0f, w_leak_p[0]);  // 1 - w_leak

  const float* xp = x   + (size_t)b * LIF_T * LIF_C + c;
  float*       op = out + (size_t)b * LIF_T * LIF_C + c;

  float bufA[LIF_U];
  float bufB[LIF_U];
  float bufC[LIF_U];
  float bufD[LIF_U];
  float Vm = 0.0f;

  // Preload chunks 0,1,2 (75 loads issued; HW throttles at vmcnt=63)
  PREFETCH(bufA, 0);
  PREFETCH(bufB, 1);
  PREFETCH(bufC, 2);

  for (int k = 0; k < LIF_NCH; k += 4) {
    PREFETCH(bufD, k + 3);                      // k+3 <= 19 always
    COMPUTE(bufA, k);
    if (k + 4 < LIF_NCH) PREFETCH(bufA, k + 4);
    COMPUTE(bufB, k + 1);
    if (k + 5 < LIF_NCH) PREFETCH(bufB, k + 5);
    COMPUTE(bufC, k + 2);
    if (k + 6 < LIF_NCH) PREFETCH(bufC, k + 6);
    COMPUTE(bufD, k + 3);
  }
}

extern "C" void kernel_launch(void* const* d_in, const int* in_sizes, int n_in,
                              void* d_out, int out_size, void* d_ws, size_t ws_size,
                              hipStream_t stream) {
  const float* x  = (const float*)d_in[0];
  const float* wi = (const float*)d_in[1];
  const float* wl = (const float*)d_in[2];
  float* out = (float*)d_out;

  const int n_threads = LIF_B * LIF_C;  // 65536
  const int block = 256;
  const int grid = n_threads / block;   // 256 blocks, ~1 per CU
  lif_kernel<<<grid, block, 0, stream>>>(x, wi, wl, out);
}

// Round 4
// 231.599 us; speedup vs baseline: 1.0533x; 1.0122x over previous
//
#include <hip/hip_runtime.h>

// LIF activation: x [B=64, T=500, C=1024] fp32, scalars w_input, w_leak.
// Per (b,c): forget=(Vm<1); Vm=relu(wi*x_t + kl*Vm*forget); spike=(Vm>1).
// Output spikes [B, T, C] fp32. One lane per (b,c) sequence; 1024 waves total
// (fixed by problem shape) -> 4 waves/CU. Memory-bound: 262 MB logical.
//
// History:
//  R1: runtime-indexed reg buffer -> scratch spill (WRITE 2x output).
//  R2: named reg double-buffer -> compiler sank loads to uses (VGPR=52),
//      ~10 loads in flight, latency-bound 82 us.
//  R3: quad buffer + asm clobbers -> still VGPR=60, 92 us. Conclusion: the
//      backend will not hold bulk loads in VGPRs, period.
//  R4 (this): stage through LDS with __builtin_amdgcn_global_load_lds(16B) —
//      side-effecting async copies the compiler cannot sink; drained by the
//      vmcnt wait at __syncthreads. Double-buffered 25-timestep chunks:
//      block = 256 threads = 256 channels of one b; chunk = 25 rows x 1 KB.
//      Prefetch issued right AFTER the barrier so the drain at the next
//      barrier overlaps the whole compute phase.
//
// __fmul_rn/__fadd_rn: spikes are exact step functions vs threshold 1.0;
// must match numpy's unfused fp32 op-by-op arithmetic (absmax=0 so far).

#define LIF_B 64
#define LIF_T 500
#define LIF_C 1024
#define LIF_TC 25                  // timesteps per LDS chunk
#define LIF_NCH (LIF_T / LIF_TC)   // 20 chunks
#define LIF_BC 256                 // channels per block

// global_load_lds: per-lane global src, wave-uniform LDS base; HW writes
// LDS at base + lane*16. Launder generic->AS pointers via uintptr_t.
#define GLOBAL_AS(p) ((__attribute__((address_space(1))) const void*)(uintptr_t)(p))
#define LDS_AS(p)    ((__attribute__((address_space(3))) void*)(uintptr_t)(p))

__global__ __launch_bounds__(256) void lif_kernel(
    const float* __restrict__ x,
    const float* __restrict__ w_input_p,
    const float* __restrict__ w_leak_p,
    float* __restrict__ out) {

  __shared__ float lds[2][LIF_TC * LIF_BC];   // 2 x 25 KB

  const int b     = blockIdx.x >> 2;          // 64 b-rows
  const int cbase = (blockIdx.x & 3) << 8;    // 4 channel groups of 256
  const int tidx  = threadIdx.x;              // 0..255
  const int wave  = tidx >> 6;                // 0..3
  const int lane  = tidx & 63;

  const float wi = w_input_p[0];
  const float kl = __fsub_rn(1.0f, w_leak_p[0]);  // 1 - w_leak

  // Block's base: row t lives at xblk + t*1024 (256 floats used from cbase).
  const float* xblk = x   + (size_t)b * LIF_T * LIF_C + cbase;
  float*       oblk = out + (size_t)b * LIF_T * LIF_C + cbase;

  // --- async-stage chunk k into lds[p]: 25 rows of 1 KB, one row per
  //     wave-instruction (64 lanes x 16 B). Rows round-robin over waves.
  auto stage = [&](int k, int p) {
    const float* src0 = xblk + (size_t)k * LIF_TC * LIF_C;
#pragma unroll
    for (int r0 = 0; r0 < LIF_TC; r0 += 4) {
      const int r = r0 + wave;
      if (r < LIF_TC) {
        const float* g = src0 + (size_t)r * LIF_C + lane * 4;  // 16 B/lane
        float* l = &lds[p][r * LIF_BC];                        // uniform base
        __builtin_amdgcn_global_load_lds(GLOBAL_AS(g), LDS_AS(l), 16, 0, 0);
      }
    }
  };

  // Prologue: stage chunk 0 into buffer 0.
  stage(0, 0);

  float Vm = 0.0f;

  for (int k = 0; k < LIF_NCH; ++k) {
    const int p = k & 1;
    // Drain chunk-k loads (they had all of compute k-1 to land) and make
    // buffer p^1 safe to overwrite (all threads done reading chunk k-1).
    __syncthreads();
    if (k + 1 < LIF_NCH) stage(k + 1, p ^ 1);

    float* orow = oblk + (size_t)k * LIF_TC * LIF_C + tidx;
#pragma unroll
    for (int r = 0; r < LIF_TC; ++r) {
      const float xt  = lds[p][r * LIF_BC + tidx];
      const float acc = (Vm < 1.0f) ? __fmul_rn(kl, Vm) : 0.0f;
      const float v   = __fadd_rn(__fmul_rn(wi, xt), acc);
      Vm = fmaxf(v, 0.0f);
      orow[(size_t)r * LIF_C] = (Vm > 1.0f) ? 1.0f : 0.0f;
    }
  }
}

extern "C" void kernel_launch(void* const* d_in, const int* in_sizes, int n_in,
                              void* d_out, int out_size, void* d_ws, size_t ws_size,
                              hipStream_t stream) {
  const float* x  = (const float*)d_in[0];
  const float* wi = (const float*)d_in[1];
  const float* wl = (const float*)d_in[2];
  float* out = (float*)d_out;

  const int grid = LIF_B * (LIF_C / LIF_BC);  // 64 * 4 = 256 blocks, ~1/CU
  lif_kernel<<<grid, 256, 0, stream>>>(x, wi, wl, out);
}